// Round 13
// baseline (363.654 us; speedup 1.0000x reference)
//
#include <hip/hip_runtime.h>
#include <hip/hip_bf16.h>
#include <math.h>

#define DIM 2048
#define NH 32
#define NKV 8
#define HD 64
#define SEQ 2048
#define BATCH 2
#define MTOT (BATCH*SEQ)          // 4096
#define QKV_N ((NH + 2*NKV)*HD)   // 3072
#define QSCALE 0.18033688011112042f   // log2(e)/8

typedef __bf16 bf16x8 __attribute__((ext_vector_type(8)));
typedef float f32x4 __attribute__((ext_vector_type(4)));

#if __has_builtin(__builtin_amdgcn_exp2f)
#define EXP2F __builtin_amdgcn_exp2f
#else
#define EXP2F exp2f
#endif

__device__ __forceinline__ void gld_lds16(const void* g, void* l) {
  __builtin_amdgcn_global_load_lds((__attribute__((address_space(1))) void*)g,
                                   (__attribute__((address_space(3))) void*)l,
                                   16, 0, 0);
}

// Counted-vmcnt phase sync (T3+T4): wait for the OLDER staged panel only (4 loads stay
// in flight), then barrier. Fused in one asm so no LDS read can be scheduled between
// the wait and the barrier (cross-wave staging hazard).
// R8 lesson: NEVER vmcnt(0) per panel at BK=32 — 16 MFMAs (~200 cyc) cannot cover a
// full drain (~600-900 cyc); the 4 newer loads must ride through both barriers.
#define PHASE_SYNC4 asm volatile("s_waitcnt vmcnt(4)\n\ts_barrier" ::: "memory")
#define PHASE_SYNC0 asm volatile("s_waitcnt vmcnt(0)\n\ts_barrier" ::: "memory")
// After compute: own ds_reads done (lgkmcnt), barrier, THEN overwrite the consumed buffer.
#define POST_SYNC   asm volatile("s_waitcnt lgkmcnt(0)\n\ts_barrier" ::: "memory")

// ---------------- fused prologue: cvt_x + transpose(wqkv) + transpose(wo), ONE dispatch ---------
// id <  8192          : cvt_x     (8192 blocks x 256 x float4 = 4096x2048 fp32 -> bf16)
// id < 8192+6144      : transpose wqkv (R=2048 x C=3072; bx in [0,96), by in [0,64))
// else (4096 blocks)  : transpose wo   (R=2048 x C=2048; bx,by in [0,64))
// Branches are block-uniform; __syncthreads only in transpose blocks (legal).
__global__ __launch_bounds__(256) void prologue_kernel(const float* __restrict__ x,
                                                       const float* __restrict__ wqkv,
                                                       const float* __restrict__ wo,
                                                       __hip_bfloat16* __restrict__ xb,
                                                       __hip_bfloat16* __restrict__ wqkvT,
                                                       __hip_bfloat16* __restrict__ woT) {
  __shared__ float tile[32][33];
  const int id = blockIdx.x;
  if (id < 8192) {
    const int i = id * 256 + threadIdx.x;
    float4 v = ((const float4*)x)[i];
    union { __hip_bfloat16 h[4]; uint2 u; } t;
    t.h[0] = __float2bfloat16(v.x); t.h[1] = __float2bfloat16(v.y);
    t.h[2] = __float2bfloat16(v.z); t.h[3] = __float2bfloat16(v.w);
    ((uint2*)xb)[i] = t.u;
    return;
  }
  const float* src;
  __hip_bfloat16* dst;
  int C, bx, by;
  if (id < 8192 + 6144) {
    const int r = id - 8192;
    src = wqkv; dst = wqkvT; C = QKV_N;
    bx = r % 96; by = r / 96;
  } else {
    const int r = id - (8192 + 6144);
    src = wo; dst = woT; C = DIM;
    bx = r & 63; by = r >> 6;
  }
  const int R = DIM;
  const int c0 = bx * 32, r0 = by * 32;
  const int tx = threadIdx.x & 31, ty = threadIdx.x >> 5;
  #pragma unroll
  for (int i = ty; i < 32; i += 8)
    tile[i][tx] = src[(size_t)(r0 + i) * C + c0 + tx];
  __syncthreads();
  #pragma unroll
  for (int i = ty; i < 32; i += 8)
    dst[(size_t)(c0 + i) * R + r0 + tx] = __float2bfloat16(tile[tx][i]);
}

// ---------------- QKV GEMM, 4-wave 128x128, BK=32 dbuf, counted-vmcnt pipeline, fused RoPE ------
// (R4 verified optimum of the structure ladder: 86.5 us, ~600 TF. Do not change sync scheme.)
// grid 768 (XCD-swizzled, bijective): wg=(id&7)*96+id>>3; bx=wg%24, by=wg/24.
__global__ __launch_bounds__(256) void gemm_qkv_rope_kernel(const __hip_bfloat16* __restrict__ A,
                                                            const __hip_bfloat16* __restrict__ Bt,
                                                            const float* __restrict__ freqs,
                                                            __hip_bfloat16* __restrict__ Qb,
                                                            __hip_bfloat16* __restrict__ Kb,
                                                            __hip_bfloat16* __restrict__ Vb) {
  __shared__ __hip_bfloat16 As[2][128 * 32];   // double buffer, 16 KB
  __shared__ __hip_bfloat16 Bs[2][128 * 32];   // 16 KB
  const int tid = threadIdx.x;
  const int w = tid >> 6, lane = tid & 63, ln = lane & 15, quad = lane >> 4;
  const int wr = w >> 1, wc = w & 1;        // 2x2 wave grid, each wave owns 64x64
  const int id = blockIdx.x;
  const int wg = (id & 7) * 96 + (id >> 3);
  const int bx = wg % 24, by = wg / 24;
  const int m0 = by * 128, n0 = bx * 128;
  const int K = DIM;
  const __hip_bfloat16* Ag = A + (size_t)(m0 + w * 16 + (lane >> 2)) * K + (lane & 3) * 8;
  const __hip_bfloat16* Bg = Bt + (size_t)(n0 + w * 16 + (lane >> 2)) * K + (lane & 3) * 8;
  f32x4 acc[4][4] = {};

  auto stage = [&](int buf, int k) {   // 4 VMEM ops per wave
    gld_lds16(Ag + k, &As[buf][w * 512]);
    gld_lds16(Ag + (size_t)64 * K + k, &As[buf][w * 512 + 2048]);
    gld_lds16(Bg + k, &Bs[buf][w * 512]);
    gld_lds16(Bg + (size_t)64 * K + k, &Bs[buf][w * 512 + 2048]);
  };
  auto compute = [&](int buf) {
    bf16x8 af[4], bf[4];
    #pragma unroll
    for (int i = 0; i < 4; i++)
      af[i] = *(const bf16x8*)&As[buf][(wr * 64 + i * 16 + ln) * 32 + quad * 8];
    #pragma unroll
    for (int j = 0; j < 4; j++)
      bf[j] = *(const bf16x8*)&Bs[buf][(wc * 64 + j * 16 + ln) * 32 + quad * 8];
    #pragma unroll
    for (int i = 0; i < 4; i++)
      #pragma unroll
      for (int j = 0; j < 4; j++)
        acc[i][j] = __builtin_amdgcn_mfma_f32_16x16x32_bf16(af[i], bf[j], acc[i][j], 0, 0, 0);
  };

  stage(0, 0);
  stage(1, 32);          // 8 loads in flight
  for (int k0 = 0; k0 + 64 < K; k0 += 64) {   // 31 iters; stages panels k0+64, k0+96 (<=2016)
    PHASE_SYNC4;         // oldest 4 (panel k0) landed; 4 newer stay in flight
    compute(0);
    POST_SYNC;           // buf0 consumed by all waves
    stage(0, k0 + 64);
    PHASE_SYNC4;         // panel k0+32 landed
    compute(1);
    POST_SYNC;
    stage(1, k0 + 96);
  }
  PHASE_SYNC4;           // panel K-64 landed (4 of panel K-32 still in flight)
  compute(0);
  PHASE_SYNC0;           // final panel landed
  compute(1);

  // epilogue: rope + head-major scatter. region is block-uniform (n0 multiple of 128; 2048,2560 are too)
  const int region = (n0 >= 2560) ? 2 : (n0 >= 2048 ? 1 : 0);
  #pragma unroll
  for (int i = 0; i < 4; i++) {
    #pragma unroll
    for (int j = 0; j < 4; j++) {
      const int n = n0 + wc * 64 + j * 16 + ln;
      const int d = n & 63;
      #pragma unroll
      for (int r = 0; r < 4; r++) {
        const int m = m0 + wr * 64 + i * 16 + quad * 4 + r;
        const int bb = m >> 11, s = m & 2047;
        float v = acc[i][j][r];
        if (region == 2) {
          Vb[((size_t)(bb * NKV + ((n - 2560) >> 6)) * SEQ + s) * HD + d] = __float2bfloat16(v);
        } else {
          float p = __shfl_xor(v, 1);
          const float2 fc = *(const float2*)&freqs[s * 64 + (d & ~1)];
          float o = (d & 1) ? (v * fc.x + p * fc.y) : (v * fc.x - p * fc.y);
          if (region == 0)
            Qb[((size_t)(bb * NH + (n >> 6)) * SEQ + s) * HD + d] = __float2bfloat16(o * QSCALE);
          else
            Kb[((size_t)(bb * NKV + ((n - 2048) >> 6)) * SEQ + s) * HD + d] = __float2bfloat16(o);
        }
      }
    }
  }
}

// ---------------- WO GEMM, 4-wave 128x128, BK=32 dbuf, counted-vmcnt pipeline, fp32 out --------
// grid 512: wg = (id&7)*64 + id>>3; bx = wg&15, by = wg>>4.
__global__ __launch_bounds__(256) void gemm_wo_kernel(const __hip_bfloat16* __restrict__ A,
                                                      const __hip_bfloat16* __restrict__ Bt,
                                                      float* __restrict__ C) {
  __shared__ __hip_bfloat16 As[2][128 * 32];
  __shared__ __hip_bfloat16 Bs[2][128 * 32];
  const int tid = threadIdx.x;
  const int w = tid >> 6, lane = tid & 63, ln = lane & 15, quad = lane >> 4;
  const int wr = w >> 1, wc = w & 1;
  const int id = blockIdx.x;
  const int wg = (id & 7) * 64 + (id >> 3);
  const int bx = wg & 15, by = wg >> 4;
  const int m0 = by * 128, n0 = bx * 128;
  const int K = DIM, N = DIM;
  const __hip_bfloat16* Ag = A + (size_t)(m0 + w * 16 + (lane >> 2)) * K + (lane & 3) * 8;
  const __hip_bfloat16* Bg = Bt + (size_t)(n0 + w * 16 + (lane >> 2)) * K + (lane & 3) * 8;
  f32x4 acc[4][4] = {};

  auto stage = [&](int buf, int k) {
    gld_lds16(Ag + k, &As[buf][w * 512]);
    gld_lds16(Ag + (size_t)64 * K + k, &As[buf][w * 512 + 2048]);
    gld_lds16(Bg + k, &Bs[buf][w * 512]);
    gld_lds16(Bg + (size_t)64 * K + k, &Bs[buf][w * 512 + 2048]);
  };
  auto compute = [&](int buf) {
    bf16x8 af[4], bf[4];
    #pragma unroll
    for (int i = 0; i < 4; i++)
      af[i] = *(const bf16x8*)&As[buf][(wr * 64 + i * 16 + ln) * 32 + quad * 8];
    #pragma unroll
    for (int j = 0; j < 4; j++)
      bf[j] = *(const bf16x8*)&Bs[buf][(wc * 64 + j * 16 + ln) * 32 + quad * 8];
    #pragma unroll
    for (int i = 0; i < 4; i++)
      #pragma unroll
      for (int j = 0; j < 4; j++)
        acc[i][j] = __builtin_amdgcn_mfma_f32_16x16x32_bf16(af[i], bf[j], acc[i][j], 0, 0, 0);
  };

  stage(0, 0);
  stage(1, 32);
  for (int k0 = 0; k0 + 64 < K; k0 += 64) {
    PHASE_SYNC4;
    compute(0);
    POST_SYNC;
    stage(0, k0 + 64);
    PHASE_SYNC4;
    compute(1);
    POST_SYNC;
    stage(1, k0 + 96);
  }
  PHASE_SYNC4;
  compute(0);
  PHASE_SYNC0;
  compute(1);

  #pragma unroll
  for (int i = 0; i < 4; i++) {
    const int r0 = m0 + wr * 64 + i * 16 + quad * 4;
    #pragma unroll
    for (int j = 0; j < 4; j++) {
      const int cc = n0 + wc * 64 + j * 16 + ln;
      #pragma unroll
      for (int r = 0; r < 4; r++)
        C[(size_t)(r0 + r) * N + cc] = acc[i][j][r];
    }
  }
}

// ---------------- flash-style causal GQA attention, KVBLK=64 / 4 blocks/CU ----------------
// No-max softmax (Q pre-scaled by log2e/8; P = exp2(s)).
// Swapped QK^T (A=K, B=Q) -> packed b64 P-stores (R10); kt-outer transient-vfr PV (R12).
// R13: KVBLK 128 -> 64. LDS = Ks 8K + Vs 9K + Ps 18K = 35.8 KB -> 4 blocks/CU (was 52 KB
// -> 3/CU; only 768 of 1024 blocks co-resident). All 1024 blocks now resident at once, so
// LPT dynamic balancing is replaced by a statically balanced t-map: t(u) = u<8 ? u : 23-u
// (slot pairs (u,u+8) sum to 15 -> any stride-32 slot set per CU has equal tile count).
// __launch_bounds__(256,4) caps VGPR at 128 to guarantee the 4th block.
// Per tile: stage K (2 gld_lds) + V scatter (16 b16) -> barrier -> QK^T + P-store + PV.
// grid 1024: xcd = id&7 owns (b,kvh) combos {2*xcd, 2*xcd+1}.
__global__ __launch_bounds__(256, 4) void attn_kernel(const __hip_bfloat16* __restrict__ Q,
                                                      const __hip_bfloat16* __restrict__ Kg,
                                                      const __hip_bfloat16* __restrict__ Vg,
                                                      __hip_bfloat16* __restrict__ O) {
  __shared__ __hip_bfloat16 Ks[64 * 64];      // 8 KB, chunk-swizzled: phys = kv*8 + (dBlk ^ (kv&7))
  __shared__ __hip_bfloat16 Vs[64 * 72];      // 9 KB, [d][s ^ ((d>>4&3)<<4)], stride 72
  __shared__ __hip_bfloat16 Ps[4][32 * 72];   // 18 KB, per-wave P, col ^ ((row>>2&3)<<4)
  const int id = blockIdx.x;
  const int xcd = id & 7, slot = id >> 3;
  const int cmb = xcd * 2 + (slot >> 6);      // 0..15
  const int b = cmb >> 3, kvh = cmb & 7;
  const int s_ = slot & 63;
  const int u = s_ >> 2;
  const int t = (u < 8) ? u : 23 - u;         // balanced: t(u) + t(u+8) = 15
  const int h = kvh * 4 + (s_ & 3);
  const int tid = threadIdx.x, w = tid >> 6, lane = tid & 63, ln = lane & 15, quad = lane >> 4;
  const size_t qbase = (size_t)(b * NH + h) * SEQ * HD;
  const size_t kbase = (size_t)(b * NKV + kvh) * SEQ * HD;

  // K gld lane mapping: phys chunk = c*256 + tid -> kv = phys>>3 (64 rows), dBlk = (tid&7)^(kv&7)
  const __hip_bfloat16* Kgl = Kg + kbase + (size_t)(tid >> 3) * 64 + (size_t)(((tid & 7) ^ ((tid >> 3) & 7)) * 8);
  // V scatter mapping: vrow 0..63 (one kv row / 4 threads), 16 cols each
  const int vrow = tid >> 2, vcb = (tid & 3) * 16, vsw = (tid & 3) << 4;
  const int psw = ((ln >> 2) & 3) << 4;       // row-derived Ps swizzle (write AND read)

  const int qgw = t * 128 + w * 32;           // wave q base
  bf16x8 qf[2][2];
  #pragma unroll
  for (int f = 0; f < 2; f++)
    #pragma unroll
    for (int kt = 0; kt < 2; kt++)
      qf[f][kt] = *(const bf16x8*)(Q + qbase + (size_t)(qgw + f * 16 + ln) * HD + kt * 32 + quad * 8);
  f32x4 Oacc[2][4] = {};
  float lrow[2][4] = {};
  union { unsigned short u[8]; bf16x8 v; } onesu;
  #pragma unroll
  for (int i = 0; i < 8; i++) onesu.u[i] = 0x3F80;
  const bf16x8 ones = onesu.v;

  const int jmax = 2 * t + 1;                 // kv tiles 0..jmax (each 64 rows)
  // preload V tile 0 (2 uint4 / thread)
  uint4 vd[2];
  #pragma unroll
  for (int cc = 0; cc < 2; cc++)
    vd[cc] = *(const uint4*)(Vg + kbase + (size_t)vrow * HD + vcb + cc * 8);

  for (int j = 0; j <= jmax; j++) {
    // async K stage (8 KB, 2 calls) + V scatter from regs (16 b16 stores)
    #pragma unroll
    for (int c = 0; c < 2; c++)
      gld_lds16(Kgl + (size_t)j * 4096 + c * 2048, &Ks[c * 2048 + w * 512]);
    #pragma unroll
    for (int cc = 0; cc < 2; cc++) {
      const __hip_bfloat16* vp = (const __hip_bfloat16*)&vd[cc];
      const int col = vcb + cc * 8;
      const int sr = vrow ^ vsw;
      #pragma unroll
      for (int e = 0; e < 8; e++)
        Vs[(col + e) * 72 + sr] = vp[e];
    }
    __syncthreads();
    // prefetch next V tile (in flight through compute)
    if (j < jmax) {
      #pragma unroll
      for (int cc = 0; cc < 2; cc++)
        vd[cc] = *(const uint4*)(Vg + kbase + (size_t)((j + 1) * 64 + vrow) * HD + vcb + cc * 8);
    }
    const int kb = j * 64;
    if (kb <= qgw + 31) {                      // wave has work this tile
      bf16x8 kf[4][2];
      #pragma unroll
      for (int nt = 0; nt < 4; nt++)
        #pragma unroll
        for (int kt = 0; kt < 2; kt++) {
          const int kv = nt * 16 + ln;
          kf[nt][kt] = *(const bf16x8*)&Ks[(kv * 8 + ((kt * 4 + quad) ^ (ln & 7))) * 8];
        }
      #pragma unroll
      for (int f = 0; f < 2; f++) {
        if (kb > qgw + f * 16 + 15) continue;  // fragment entirely above diagonal
        f32x4 sf[4];
        #pragma unroll
        for (int nt = 0; nt < 4; nt++) {
          f32x4 s = {};
          // SWAPPED: A=K, B=Q -> lane holds P[kv = nt*16+quad*4+r][q = f*16+ln]
          s = __builtin_amdgcn_mfma_f32_16x16x32_bf16(kf[nt][0], qf[f][0], s, 0, 0, 0);
          s = __builtin_amdgcn_mfma_f32_16x16x32_bf16(kf[nt][1], qf[f][1], s, 0, 0, 0);
          sf[nt] = s;
        }
        if (kb + 63 > qgw + f * 16) {          // tile crosses diagonal for this fragment
          const int qv = qgw + f * 16 + ln;
          #pragma unroll
          for (int nt = 0; nt < 4; nt++) {
            const int kg = kb + nt * 16 + quad * 4;
            #pragma unroll
            for (int r = 0; r < 4; r++)
              if (kg + r > qv) sf[nt][r] = -1.0e38f;
          }
        }
        // packed P-store: one b64 per (f,nt) -> row f*16+ln, cols nt*16+quad*4 .. +3
        #pragma unroll
        for (int nt = 0; nt < 4; nt++) {
          union { __hip_bfloat16 h[4]; uint2 u; } pk;
          #pragma unroll
          for (int r = 0; r < 4; r++)
            pk.h[r] = __float2bfloat16(EXP2F(sf[nt][r]));
          *(uint2*)&Ps[w][(f * 16 + ln) * 72 + ((nt * 16 + quad * 4) ^ psw)] = pk.u;
        }
      }
      // kt-outer PV: vfr transient (16 VGPR, scoped per kt); lsa accumulates row-sum
      f32x4 lsa[2] = {};
      #pragma unroll
      for (int kt = 0; kt < 2; kt++) {
        bf16x8 vfr[4];
        #pragma unroll
        for (int dt = 0; dt < 4; dt++)
          vfr[dt] = *(const bf16x8*)&Vs[(dt * 16 + ln) * 72 + ((kt * 32 + quad * 8) ^ (dt << 4))];
        #pragma unroll
        for (int f = 0; f < 2; f++) {
          if (kb > qgw + f * 16 + 15) continue;
          bf16x8 pf = *(const bf16x8*)&Ps[w][(f * 16 + ln) * 72 + ((kt * 32 + quad * 8) ^ psw)];
          lsa[f] = __builtin_amdgcn_mfma_f32_16x16x32_bf16(pf, ones, lsa[f], 0, 0, 0);
          #pragma unroll
          for (int dt = 0; dt < 4; dt++)
            Oacc[f][dt] = __builtin_amdgcn_mfma_f32_16x16x32_bf16(pf, vfr[dt], Oacc[f][dt], 0, 0, 0);
        }
      }
      #pragma unroll
      for (int f = 0; f < 2; f++) {
        if (kb > qgw + f * 16 + 15) continue;
        #pragma unroll
        for (int r = 0; r < 4; r++) lrow[f][r] += lsa[f][r];
      }
    }
    __syncthreads();   // protects Ks/Vs before next staging; all waves reach it
  }
  // epilogue: out[b][s][h*64+d] = O/l
  #pragma unroll
  for (int f = 0; f < 2; f++) {
    const int so = qgw + f * 16 + quad * 4;
    #pragma unroll
    for (int r = 0; r < 4; r++) {
      const float inv = 1.0f / lrow[f][r];
      #pragma unroll
      for (int dt = 0; dt < 4; dt++)
        O[((size_t)(b * SEQ) + so + r) * DIM + h * HD + dt * 16 + ln] =
            __float2bfloat16(Oacc[f][dt][r] * inv);
    }
  }
}

extern "C" void kernel_launch(void* const* d_in, const int* in_sizes, int n_in,
                              void* d_out, int out_size, void* d_ws, size_t ws_size,
                              hipStream_t stream) {
  const float* x     = (const float*)d_in[0];
  const float* freqs = (const float*)d_in[1];
  const float* wqkv  = (const float*)d_in[2];
  const float* wo    = (const float*)d_in[3];
  float* out = (float*)d_out;

  char* ws = (char*)d_ws;
  __hip_bfloat16* xb    = (__hip_bfloat16*)ws; ws += (size_t)MTOT * DIM * 2;
  __hip_bfloat16* wqkvT = (__hip_bfloat16*)ws; ws += (size_t)QKV_N * DIM * 2;
  __hip_bfloat16* woT   = (__hip_bfloat16*)ws; ws += (size_t)DIM * DIM * 2;
  __hip_bfloat16* Qb    = (__hip_bfloat16*)ws; ws += (size_t)BATCH * NH * SEQ * HD * 2;
  __hip_bfloat16* Kb    = (__hip_bfloat16*)ws; ws += (size_t)BATCH * NKV * SEQ * HD * 2;
  __hip_bfloat16* Vb    = (__hip_bfloat16*)ws; ws += (size_t)BATCH * NKV * SEQ * HD * 2;
  __hip_bfloat16* attnb = (__hip_bfloat16*)ws; ws += (size_t)MTOT * DIM * 2;

  prologue_kernel<<<8192 + 6144 + 4096, 256, 0, stream>>>(x, wqkv, wo, xb, wqkvT, woT);
  gemm_qkv_rope_kernel<<<768, 256, 0, stream>>>(xb, wqkvT, freqs, Qb, Kb, Vb);
  attn_kernel<<<1024, 256, 0, stream>>>(Qb, Kb, Vb, attnb);
  gemm_wo_kernel<<<512, 256, 0, stream>>>(attnb, woT, out);
}

// Round 14
// 295.791 us; speedup vs baseline: 1.2294x; 1.2294x over previous
//
#include <hip/hip_runtime.h>
#include <hip/hip_bf16.h>
#include <math.h>

#define DIM 2048
#define NH 32
#define NKV 8
#define HD 64
#define SEQ 2048
#define BATCH 2
#define MTOT (BATCH*SEQ)          // 4096
#define QKV_N ((NH + 2*NKV)*HD)   // 3072
#define QSCALE 0.18033688011112042f   // log2(e)/8

typedef __bf16 bf16x8 __attribute__((ext_vector_type(8)));
typedef float f32x4 __attribute__((ext_vector_type(4)));

#if __has_builtin(__builtin_amdgcn_exp2f)
#define EXP2F __builtin_amdgcn_exp2f
#else
#define EXP2F exp2f
#endif

__device__ __forceinline__ void gld_lds16(const void* g, void* l) {
  __builtin_amdgcn_global_load_lds((__attribute__((address_space(1))) void*)g,
                                   (__attribute__((address_space(3))) void*)l,
                                   16, 0, 0);
}

// Counted-vmcnt phase sync (T3+T4): wait for the OLDER staged panel only (4 loads stay
// in flight), then barrier. Fused in one asm so no LDS read can be scheduled between
// the wait and the barrier (cross-wave staging hazard).
// R8 lesson: NEVER vmcnt(0) per panel at BK=32 — 16 MFMAs (~200 cyc) cannot cover a
// full drain (~600-900 cyc); the 4 newer loads must ride through both barriers.
// R13 lesson: same law in attn — halving the KV tile doubles exposed drains and loses.
#define PHASE_SYNC4 asm volatile("s_waitcnt vmcnt(4)\n\ts_barrier" ::: "memory")
#define PHASE_SYNC0 asm volatile("s_waitcnt vmcnt(0)\n\ts_barrier" ::: "memory")
// After compute: own ds_reads done (lgkmcnt), barrier, THEN overwrite the consumed buffer.
#define POST_SYNC   asm volatile("s_waitcnt lgkmcnt(0)\n\ts_barrier" ::: "memory")

// ---------------- fused prologue: cvt_x + transpose(wqkv) + transpose(wo), ONE dispatch ---------
// id <  8192          : cvt_x     (8192 blocks x 256 x float4 = 4096x2048 fp32 -> bf16)
// id < 8192+6144      : transpose wqkv (R=2048 x C=3072; bx in [0,96), by in [0,64))
// else (4096 blocks)  : transpose wo   (R=2048 x C=2048; bx,by in [0,64))
// Branches are block-uniform; __syncthreads only in transpose blocks (legal).
__global__ __launch_bounds__(256) void prologue_kernel(const float* __restrict__ x,
                                                       const float* __restrict__ wqkv,
                                                       const float* __restrict__ wo,
                                                       __hip_bfloat16* __restrict__ xb,
                                                       __hip_bfloat16* __restrict__ wqkvT,
                                                       __hip_bfloat16* __restrict__ woT) {
  __shared__ float tile[32][33];
  const int id = blockIdx.x;
  if (id < 8192) {
    const int i = id * 256 + threadIdx.x;
    float4 v = ((const float4*)x)[i];
    union { __hip_bfloat16 h[4]; uint2 u; } t;
    t.h[0] = __float2bfloat16(v.x); t.h[1] = __float2bfloat16(v.y);
    t.h[2] = __float2bfloat16(v.z); t.h[3] = __float2bfloat16(v.w);
    ((uint2*)xb)[i] = t.u;
    return;
  }
  const float* src;
  __hip_bfloat16* dst;
  int C, bx, by;
  if (id < 8192 + 6144) {
    const int r = id - 8192;
    src = wqkv; dst = wqkvT; C = QKV_N;
    bx = r % 96; by = r / 96;
  } else {
    const int r = id - (8192 + 6144);
    src = wo; dst = woT; C = DIM;
    bx = r & 63; by = r >> 6;
  }
  const int R = DIM;
  const int c0 = bx * 32, r0 = by * 32;
  const int tx = threadIdx.x & 31, ty = threadIdx.x >> 5;
  #pragma unroll
  for (int i = ty; i < 32; i += 8)
    tile[i][tx] = src[(size_t)(r0 + i) * C + c0 + tx];
  __syncthreads();
  #pragma unroll
  for (int i = ty; i < 32; i += 8)
    dst[(size_t)(c0 + i) * R + r0 + tx] = __float2bfloat16(tile[tx][i]);
}

// ---------------- QKV GEMM, 4-wave 128x128, BK=32 dbuf, counted-vmcnt pipeline, fused RoPE ------
// (R4 verified optimum of the structure ladder: 86.5 us, ~600 TF. Do not change sync scheme.)
// grid 768 (XCD-swizzled, bijective): wg=(id&7)*96+id>>3; bx=wg%24, by=wg/24.
__global__ __launch_bounds__(256) void gemm_qkv_rope_kernel(const __hip_bfloat16* __restrict__ A,
                                                            const __hip_bfloat16* __restrict__ Bt,
                                                            const float* __restrict__ freqs,
                                                            __hip_bfloat16* __restrict__ Qb,
                                                            __hip_bfloat16* __restrict__ Kb,
                                                            __hip_bfloat16* __restrict__ Vb) {
  __shared__ __hip_bfloat16 As[2][128 * 32];   // double buffer, 16 KB
  __shared__ __hip_bfloat16 Bs[2][128 * 32];   // 16 KB
  const int tid = threadIdx.x;
  const int w = tid >> 6, lane = tid & 63, ln = lane & 15, quad = lane >> 4;
  const int wr = w >> 1, wc = w & 1;        // 2x2 wave grid, each wave owns 64x64
  const int id = blockIdx.x;
  const int wg = (id & 7) * 96 + (id >> 3);
  const int bx = wg % 24, by = wg / 24;
  const int m0 = by * 128, n0 = bx * 128;
  const int K = DIM;
  const __hip_bfloat16* Ag = A + (size_t)(m0 + w * 16 + (lane >> 2)) * K + (lane & 3) * 8;
  const __hip_bfloat16* Bg = Bt + (size_t)(n0 + w * 16 + (lane >> 2)) * K + (lane & 3) * 8;
  f32x4 acc[4][4] = {};

  auto stage = [&](int buf, int k) {   // 4 VMEM ops per wave
    gld_lds16(Ag + k, &As[buf][w * 512]);
    gld_lds16(Ag + (size_t)64 * K + k, &As[buf][w * 512 + 2048]);
    gld_lds16(Bg + k, &Bs[buf][w * 512]);
    gld_lds16(Bg + (size_t)64 * K + k, &Bs[buf][w * 512 + 2048]);
  };
  auto compute = [&](int buf) {
    bf16x8 af[4], bf[4];
    #pragma unroll
    for (int i = 0; i < 4; i++)
      af[i] = *(const bf16x8*)&As[buf][(wr * 64 + i * 16 + ln) * 32 + quad * 8];
    #pragma unroll
    for (int j = 0; j < 4; j++)
      bf[j] = *(const bf16x8*)&Bs[buf][(wc * 64 + j * 16 + ln) * 32 + quad * 8];
    #pragma unroll
    for (int i = 0; i < 4; i++)
      #pragma unroll
      for (int j = 0; j < 4; j++)
        acc[i][j] = __builtin_amdgcn_mfma_f32_16x16x32_bf16(af[i], bf[j], acc[i][j], 0, 0, 0);
  };

  stage(0, 0);
  stage(1, 32);          // 8 loads in flight
  for (int k0 = 0; k0 + 64 < K; k0 += 64) {   // 31 iters; stages panels k0+64, k0+96 (<=2016)
    PHASE_SYNC4;         // oldest 4 (panel k0) landed; 4 newer stay in flight
    compute(0);
    POST_SYNC;           // buf0 consumed by all waves
    stage(0, k0 + 64);
    PHASE_SYNC4;         // panel k0+32 landed
    compute(1);
    POST_SYNC;
    stage(1, k0 + 96);
  }
  PHASE_SYNC4;           // panel K-64 landed (4 of panel K-32 still in flight)
  compute(0);
  PHASE_SYNC0;           // final panel landed
  compute(1);

  // epilogue: rope + head-major scatter. region is block-uniform (n0 multiple of 128; 2048,2560 are too)
  const int region = (n0 >= 2560) ? 2 : (n0 >= 2048 ? 1 : 0);
  #pragma unroll
  for (int i = 0; i < 4; i++) {
    #pragma unroll
    for (int j = 0; j < 4; j++) {
      const int n = n0 + wc * 64 + j * 16 + ln;
      const int d = n & 63;
      #pragma unroll
      for (int r = 0; r < 4; r++) {
        const int m = m0 + wr * 64 + i * 16 + quad * 4 + r;
        const int bb = m >> 11, s = m & 2047;
        float v = acc[i][j][r];
        if (region == 2) {
          Vb[((size_t)(bb * NKV + ((n - 2560) >> 6)) * SEQ + s) * HD + d] = __float2bfloat16(v);
        } else {
          float p = __shfl_xor(v, 1);
          const float2 fc = *(const float2*)&freqs[s * 64 + (d & ~1)];
          float o = (d & 1) ? (v * fc.x + p * fc.y) : (v * fc.x - p * fc.y);
          if (region == 0)
            Qb[((size_t)(bb * NH + (n >> 6)) * SEQ + s) * HD + d] = __float2bfloat16(o * QSCALE);
          else
            Kb[((size_t)(bb * NKV + ((n - 2048) >> 6)) * SEQ + s) * HD + d] = __float2bfloat16(o);
        }
      }
    }
  }
}

// ---------------- WO GEMM, 4-wave 128x128, BK=32 dbuf, counted-vmcnt pipeline, fp32 out --------
// grid 512: wg = (id&7)*64 + id>>3; bx = wg&15, by = wg>>4.
__global__ __launch_bounds__(256) void gemm_wo_kernel(const __hip_bfloat16* __restrict__ A,
                                                      const __hip_bfloat16* __restrict__ Bt,
                                                      float* __restrict__ C) {
  __shared__ __hip_bfloat16 As[2][128 * 32];
  __shared__ __hip_bfloat16 Bs[2][128 * 32];
  const int tid = threadIdx.x;
  const int w = tid >> 6, lane = tid & 63, ln = lane & 15, quad = lane >> 4;
  const int wr = w >> 1, wc = w & 1;
  const int id = blockIdx.x;
  const int wg = (id & 7) * 64 + (id >> 3);
  const int bx = wg & 15, by = wg >> 4;
  const int m0 = by * 128, n0 = bx * 128;
  const int K = DIM, N = DIM;
  const __hip_bfloat16* Ag = A + (size_t)(m0 + w * 16 + (lane >> 2)) * K + (lane & 3) * 8;
  const __hip_bfloat16* Bg = Bt + (size_t)(n0 + w * 16 + (lane >> 2)) * K + (lane & 3) * 8;
  f32x4 acc[4][4] = {};

  auto stage = [&](int buf, int k) {
    gld_lds16(Ag + k, &As[buf][w * 512]);
    gld_lds16(Ag + (size_t)64 * K + k, &As[buf][w * 512 + 2048]);
    gld_lds16(Bg + k, &Bs[buf][w * 512]);
    gld_lds16(Bg + (size_t)64 * K + k, &Bs[buf][w * 512 + 2048]);
  };
  auto compute = [&](int buf) {
    bf16x8 af[4], bf[4];
    #pragma unroll
    for (int i = 0; i < 4; i++)
      af[i] = *(const bf16x8*)&As[buf][(wr * 64 + i * 16 + ln) * 32 + quad * 8];
    #pragma unroll
    for (int j = 0; j < 4; j++)
      bf[j] = *(const bf16x8*)&Bs[buf][(wc * 64 + j * 16 + ln) * 32 + quad * 8];
    #pragma unroll
    for (int i = 0; i < 4; i++)
      #pragma unroll
      for (int j = 0; j < 4; j++)
        acc[i][j] = __builtin_amdgcn_mfma_f32_16x16x32_bf16(af[i], bf[j], acc[i][j], 0, 0, 0);
  };

  stage(0, 0);
  stage(1, 32);
  for (int k0 = 0; k0 + 64 < K; k0 += 64) {
    PHASE_SYNC4;
    compute(0);
    POST_SYNC;
    stage(0, k0 + 64);
    PHASE_SYNC4;
    compute(1);
    POST_SYNC;
    stage(1, k0 + 96);
  }
  PHASE_SYNC4;
  compute(0);
  PHASE_SYNC0;
  compute(1);

  #pragma unroll
  for (int i = 0; i < 4; i++) {
    const int r0 = m0 + wr * 64 + i * 16 + quad * 4;
    #pragma unroll
    for (int j = 0; j < 4; j++) {
      const int cc = n0 + wc * 64 + j * 16 + ln;
      #pragma unroll
      for (int r = 0; r < 4; r++)
        C[(size_t)(r0 + r) * N + cc] = acc[i][j][r];
    }
  }
}

// ---------------- flash-style causal GQA attention (R10 version, session best) ----------------
// No-max softmax (Q pre-scaled by log2e/8; P = exp2(s)).
// Swapped QK^T (A=K, B=Q) -> packed b64 P-stores (R10, +13.5us vs scalar stores).
// KVBLK=128, 3 blocks/CU (R13 showed KVBLK=64 doubles exposed K-stage drains and loses;
// R11 showed vf-hoist crosses the 128-VGPR cliff; R12 kt-outer was neutral).
// grid 1024 (1-D, XCD-swizzled): xcd = id&7 owns (b,kvh) combos {2*xcd, 2*xcd+1};
// within combo: t = 15-(slot>>2) (LPT), head group g = slot&3.
// 4 waves x 32 q-rows (128-row q-tile); KV tile 128 per barrier-pair, two 64-KV sub-rounds.
__global__ __launch_bounds__(256, 3) void attn_kernel(const __hip_bfloat16* __restrict__ Q,
                                                      const __hip_bfloat16* __restrict__ Kg,
                                                      const __hip_bfloat16* __restrict__ Vg,
                                                      __hip_bfloat16* __restrict__ O) {
  __shared__ __hip_bfloat16 Ks[128 * 64];     // chunk-swizzled: phys = kv*8 + (dBlk ^ (kv&7))
  __shared__ __hip_bfloat16 Vs[64 * 136];     // [d][s ^ ((d>>4&3)<<4)], stride 136
  __shared__ __hip_bfloat16 Ps[4][32 * 72];   // per-wave P, col ^ ((row>>2&3)<<4), stride 72
  const int id = blockIdx.x;
  const int xcd = id & 7, slot = id >> 3;
  const int cmb = xcd * 2 + (slot >> 6);      // 0..15
  const int b = cmb >> 3, kvh = cmb & 7;
  const int s_ = slot & 63;
  const int t = 15 - (s_ >> 2);               // big tiles first per XCD
  const int h = kvh * 4 + (s_ & 3);
  const int tid = threadIdx.x, w = tid >> 6, lane = tid & 63, ln = lane & 15, quad = lane >> 4;
  const size_t qbase = (size_t)(b * NH + h) * SEQ * HD;
  const size_t kbase = (size_t)(b * NKV + kvh) * SEQ * HD;

  // K gld lane mapping: phys chunk = c*256 + tid -> kv = phys>>3, dBlk = (phys&7)^(kv&7)
  const __hip_bfloat16* Kgl = Kg + kbase + (size_t)(tid >> 3) * 64 + (size_t)(((tid & 7) ^ ((tid >> 3) & 7)) * 8);
  // V scatter mapping (2-way free)
  const int vrow = tid >> 2, vcb = (tid & 3) * 16, vsw = (tid & 3) << 4;
  const int psw = ((ln >> 2) & 3) << 4;       // row-derived Ps swizzle (write AND read)

  const int qgw = t * 128 + w * 32;
  bf16x8 qf[2][2];
  #pragma unroll
  for (int f = 0; f < 2; f++)
    #pragma unroll
    for (int kt = 0; kt < 2; kt++)
      qf[f][kt] = *(const bf16x8*)(Q + qbase + (size_t)(qgw + f * 16 + ln) * HD + kt * 32 + quad * 8);
  f32x4 Oacc[2][4] = {};
  float lrow[2][4] = {};
  union { unsigned short u[8]; bf16x8 v; } onesu;
  #pragma unroll
  for (int i = 0; i < 8; i++) onesu.u[i] = 0x3F80;
  const bf16x8 ones = onesu.v;

  // preload V tile 0
  uint4 vd[2][2];
  #pragma unroll
  for (int bt = 0; bt < 2; bt++)
    #pragma unroll
    for (int cc = 0; cc < 2; cc++)
      vd[bt][cc] = *(const uint4*)(Vg + kbase + (size_t)(bt * 64 + vrow) * HD + vcb + cc * 8);

  for (int j = 0; j <= t; j++) {
    // async K stage (16 KB, 4 calls) + V scatter from regs
    #pragma unroll
    for (int c = 0; c < 4; c++)
      gld_lds16(Kgl + (size_t)j * 8192 + c * 2048, &Ks[c * 2048 + w * 512]);
    #pragma unroll
    for (int bt = 0; bt < 2; bt++)
      #pragma unroll
      for (int cc = 0; cc < 2; cc++) {
        const __hip_bfloat16* vp = (const __hip_bfloat16*)&vd[bt][cc];
        const int col = vcb + cc * 8;
        const int sr = (bt * 64 + vrow) ^ vsw;
        #pragma unroll
        for (int e = 0; e < 8; e++)
          Vs[(col + e) * 136 + sr] = vp[e];
      }
    __syncthreads();
    // prefetch next V tile (stays in flight through compute)
    if (j < t) {
      #pragma unroll
      for (int bt = 0; bt < 2; bt++)
        #pragma unroll
        for (int cc = 0; cc < 2; cc++)
          vd[bt][cc] = *(const uint4*)(Vg + kbase + (size_t)((j + 1) * 128 + bt * 64 + vrow) * HD + vcb + cc * 8);
    }
    const bool lastIter = (j == t);
    #pragma unroll
    for (int s2 = 0; s2 < 2; s2++) {
      if (lastIter && s2 * 64 > w * 32 + 31) continue;   // wave entirely above diagonal
      bf16x8 kf[4][2];
      #pragma unroll
      for (int nt = 0; nt < 4; nt++)
        #pragma unroll
        for (int kt = 0; kt < 2; kt++) {
          const int kv = s2 * 64 + nt * 16 + ln;
          kf[nt][kt] = *(const bf16x8*)&Ks[(kv * 8 + ((kt * 4 + quad) ^ (ln & 7))) * 8];
        }
      #pragma unroll
      for (int f = 0; f < 2; f++) {
        if (lastIter && s2 * 64 > w * 32 + f * 16 + 15) continue;
        f32x4 sf[4];
        #pragma unroll
        for (int nt = 0; nt < 4; nt++) {
          f32x4 s = {};
          // SWAPPED: A=K, B=Q -> lane holds P[kv = s2*64+nt*16+quad*4+r][q = f*16+ln]
          s = __builtin_amdgcn_mfma_f32_16x16x32_bf16(kf[nt][0], qf[f][0], s, 0, 0, 0);
          s = __builtin_amdgcn_mfma_f32_16x16x32_bf16(kf[nt][1], qf[f][1], s, 0, 0, 0);
          sf[nt] = s;
        }
        if (lastIter && s2 * 64 + 63 > w * 32 + f * 16) {
          const int qv = w * 32 + f * 16 + ln;
          #pragma unroll
          for (int nt = 0; nt < 4; nt++) {
            const int kg = s2 * 64 + nt * 16 + quad * 4;
            #pragma unroll
            for (int r = 0; r < 4; r++)
              if (kg + r > qv) sf[nt][r] = -1.0e38f;
          }
        }
        // packed P-store: one b64 per (f,nt) -> row f*16+ln, cols nt*16+quad*4 .. +3
        #pragma unroll
        for (int nt = 0; nt < 4; nt++) {
          union { __hip_bfloat16 h[4]; uint2 u; } pk;
          #pragma unroll
          for (int r = 0; r < 4; r++)
            pk.h[r] = __float2bfloat16(EXP2F(sf[nt][r]));
          *(uint2*)&Ps[w][(f * 16 + ln) * 72 + ((nt * 16 + quad * 4) ^ psw)] = pk.u;
        }
      }
      #pragma unroll
      for (int f = 0; f < 2; f++) {
        if (lastIter && s2 * 64 > w * 32 + f * 16 + 15) continue;
        f32x4 ls = {};
        #pragma unroll
        for (int kt = 0; kt < 2; kt++) {
          bf16x8 pf = *(const bf16x8*)&Ps[w][(f * 16 + ln) * 72 + ((kt * 32 + quad * 8) ^ psw)];
          ls = __builtin_amdgcn_mfma_f32_16x16x32_bf16(pf, ones, ls, 0, 0, 0);
          #pragma unroll
          for (int dt = 0; dt < 4; dt++) {
            bf16x8 vf = *(const bf16x8*)&Vs[(dt * 16 + ln) * 136 + s2 * 64 + ((kt * 32 + quad * 8) ^ (dt << 4))];
            Oacc[f][dt] = __builtin_amdgcn_mfma_f32_16x16x32_bf16(pf, vf, Oacc[f][dt], 0, 0, 0);
          }
        }
        #pragma unroll
        for (int r = 0; r < 4; r++) lrow[f][r] += ls[r];
      }
    }
    __syncthreads();   // protects Ks/Vs before next staging; all waves reach it
  }
  // epilogue: out[b][s][h*64+d] = O/l
  #pragma unroll
  for (int f = 0; f < 2; f++) {
    const int so = qgw + f * 16 + quad * 4;
    #pragma unroll
    for (int r = 0; r < 4; r++) {
      const float inv = 1.0f / lrow[f][r];
      #pragma unroll
      for (int dt = 0; dt < 4; dt++)
        O[((size_t)(b * SEQ) + so + r) * DIM + h * HD + dt * 16 + ln] =
            __float2bfloat16(Oacc[f][dt][r] * inv);
    }
  }
}

extern "C" void kernel_launch(void* const* d_in, const int* in_sizes, int n_in,
                              void* d_out, int out_size, void* d_ws, size_t ws_size,
                              hipStream_t stream) {
  const float* x     = (const float*)d_in[0];
  const float* freqs = (const float*)d_in[1];
  const float* wqkv  = (const float*)d_in[2];
  const float* wo    = (const float*)d_in[3];
  float* out = (float*)d_out;

  char* ws = (char*)d_ws;
  __hip_bfloat16* xb    = (__hip_bfloat16*)ws; ws += (size_t)MTOT * DIM * 2;
  __hip_bfloat16* wqkvT = (__hip_bfloat16*)ws; ws += (size_t)QKV_N * DIM * 2;
  __hip_bfloat16* woT   = (__hip_bfloat16*)ws; ws += (size_t)DIM * DIM * 2;
  __hip_bfloat16* Qb    = (__hip_bfloat16*)ws; ws += (size_t)BATCH * NH * SEQ * HD * 2;
  __hip_bfloat16* Kb    = (__hip_bfloat16*)ws; ws += (size_t)BATCH * NKV * SEQ * HD * 2;
  __hip_bfloat16* Vb    = (__hip_bfloat16*)ws; ws += (size_t)BATCH * NKV * SEQ * HD * 2;
  __hip_bfloat16* attnb = (__hip_bfloat16*)ws; ws += (size_t)MTOT * DIM * 2;

  prologue_kernel<<<8192 + 6144 + 4096, 256, 0, stream>>>(x, wqkv, wo, xb, wqkvT, woT);
  gemm_qkv_rope_kernel<<<768, 256, 0, stream>>>(xb, wqkvT, freqs, Qb, Kb, Vb);
  attn_kernel<<<1024, 256, 0, stream>>>(Qb, Kb, Vb, attnb);
  gemm_wo_kernel<<<512, 256, 0, stream>>>(attnb, woT, out);
}